// Round 9
// baseline (584.584 us; speedup 1.0000x reference)
//
#include <hip/hip_runtime.h>
#include <math.h>

#define BT 32
#define KC 256
#define HH 64
#define WW 64
#define TT 4
#define BB 8
#define NN2 16
#define NC 128   // BB*NN2 anchors
#define HW 4096

// block-role layout of the mega kernel
#define CE_BLOCKS   768      // 24 frames * 32 tiles
#define OHEM_BLOCKS 256      // 32 frames * 8 channel groups
#define REF_BLOCKS  128      // one per logits row
#define MEGA_BLOCKS (CE_BLOCKS + OHEM_BLOCKS + REF_BLOCKS)

// ---------------------------------------------------------------------------
// helpers
// ---------------------------------------------------------------------------
__device__ __forceinline__ int affine_nearest(const float* __restrict__ th,
                                              float gx, float gy, int& valid) {
    // theta row-major [2][3]; PyTorch affine_grid align_corners=False convention
    float sx = th[0] * gx + th[1] * gy + th[2];
    float sy = th[3] * gx + th[4] * gy + th[5];
    float ix = (sx + 1.0f) * 32.0f - 0.5f;
    float iy = (sy + 1.0f) * 32.0f - 0.5f;
    int jx = (int)rintf(ix);   // round half to even == jnp.rint
    int jy = (int)rintf(iy);
    valid = (jx >= 0 && jx < WW && jy >= 0 && jy < HH);
    jx = min(WW - 1, max(0, jx));
    jy = min(HH - 1, max(0, jy));
    return jy * WW + jx;
}

__device__ __forceinline__ float reflect64(float c) {
    // PyTorch reflect (align_corners=False): reflect about (-0.5, 63.5)
    float x = fabsf(c + 0.5f);
    x = fmodf(x, 128.0f);
    x = (x >= 64.0f) ? (128.0f - x) : x;
    return x - 0.5f;
}

// ---------------------------------------------------------------------------
// prep kernel: block 0 zeros accumulators; blocks 1..128 build q1T;
// blocks 129..256 build ref anchors x1,y1
// ---------------------------------------------------------------------------
__global__ __launch_bounds__(256) void prep_kernel(
        const float* __restrict__ k1, const float* __restrict__ k2,
        const float* __restrict__ am1, const float* __restrict__ am2,
        const int* __restrict__ hw_index, const int* __restrict__ hw_index_ref,
        float* __restrict__ wsf, float* __restrict__ q1T,
        float* __restrict__ x1, float* __restrict__ y1) {
    int bi = blockIdx.x;
    int tid = threadIdx.x;
    if (bi == 0) {
        if (tid < 64) wsf[tid] = 0.0f;
    } else if (bi <= 128) {
        int c = bi - 1;              // anchor 0..127
        int b = c >> 4;              // video
        int idx = hw_index[c];       // position in frame 0 of video b
        q1T[tid * NC + c] = k1[((b * TT) * KC + tid) * HW + idx];
    } else {
        int c = bi - 129;
        int b = c >> 4;
        int n = b * 4;               // first frame of video
        int idx = hw_index_ref[c];
        int ha = idx >> 6, wa = idx & 63;
        float gx = (wa + 0.5f) * 0.03125f - 1.0f;
        float gy = (ha + 0.5f) * 0.03125f - 1.0f;
        int v1, v2;
        int sp1 = affine_nearest(am1 + n * 6, gx, gy, v1);
        int sp2 = affine_nearest(am2 + n * 6, gx, gy, v2);
        x1[c * KC + tid] = v1 ? k1[(n * KC + tid) * HW + sp1] : 0.0f;
        y1[c * KC + tid] = v2 ? k2[(n * KC + tid) * HW + sp2] : 0.0f;
    }
}

// ---------------------------------------------------------------------------
// shared-memory union for the mega kernel
// ---------------------------------------------------------------------------
union MegaSmem {
    struct {
        float As[16][128];      // k1 gathered tile (K-slice x positions)
        float As2[16][128];     // k2 gathered tile
        float Bs[16][128];      // q1T tile (K-slice x anchors)
        int   sposLds[2][128];
        int   pseudoLds[128];
        float wpart[4];
    } ce;
    struct {
        unsigned short spos[HW];
        float wpart[4];
    } oh;
    struct {
        float xr[256];
        float wred[2];
        float wsum[2];
        float liish;
    } rf;
};

// ---------------------------------------------------------------------------
// mega kernel: CE blocks (compute-bound) + OHEM blocks (memory-bound) +
// ref-loss blocks, co-resident so memory traffic hides under VALU work.
// ---------------------------------------------------------------------------
__global__ __launch_bounds__(256, 2) void mega_kernel(
        const float* __restrict__ k1, const float* __restrict__ k2,
        const float* __restrict__ am1, const float* __restrict__ am2,
        const float* __restrict__ aff_grid, const float* __restrict__ q1T,
        const float* __restrict__ x1, const float* __restrict__ y1,
        float* __restrict__ wsf) {

    __shared__ __align__(16) MegaSmem sm;
    int tid = threadIdx.x;

    if (blockIdx.x < CE_BLOCKS) {
        // ================= CE path =================
        // XCD-aware remap: dispatcher assigns XCD = blockIdx % 8 (round-robin).
        // Map so all 32 tiles of a frame share blockIdx mod 8 -> one XCD's L2
        // caches that frame's 8 MB (k1+k2) once instead of 8x.
        // Bijective on [0,768): g = fi%8 + 8*tile + 256*(fi/8).
        int g    = blockIdx.x;
        int fi   = (g & 7) + 8 * (g >> 8);  // 0..23
        int tile = (g >> 3) & 31;
        int vid  = fi / 3;
        int t    = fi - vid * 3 + 1;        // 1..3
        int n    = vid * 4 + t;             // frame

        // ---- phase 0: warped nearest positions for both grids ----
        {
            int which = tid >> 7;           // 0 -> g1, 1 -> g2
            int lp    = tid & 127;
            int p = tile * 128 + lp;
            int h = p >> 6, w = p & 63;
            float gx = (w + 0.5f) * 0.03125f - 1.0f;
            float gy = (h + 0.5f) * 0.03125f - 1.0f;
            const float* th = (which == 0 ? am1 : am2) + n * 6;
            int valid;
            int sp = affine_nearest(th, gx, gy, valid);
            sm.ce.sposLds[which][lp] = valid ? sp : -1;
        }
        __syncthreads();

        const float* k1f = k1 + n * KC * HW;
        const float* k2f = k2 + n * KC * HW;
        int pl    = tid & 127;
        int khalf = tid >> 7;               // 0/1

        // thread mappings
        int tp = tid >> 4;                  // main GEMM: position group 0..15
        int tc = tid & 15;                  // main GEMM: anchor group 0..15
        int p2   = tid >> 1;                // pseudo: position 0..127
        int half = tid & 1;                 // pseudo: low/high 8 anchors

        int sp1g = sm.ce.sposLds[0][pl];
        int sp2g = sm.ce.sposLds[1][pl];

        // ---- fused K-loop: main 128x128 GEMM (k1 vs q1T) and pseudo-label
        //      dots (k2 vs q1T's 16 in-video columns) share staging+barriers.
        // Column/row split per thread is {g*4, g*4+64}: float4 reads start at
        // bank (g*4)%32 -> 2-way lane aliasing (free) instead of 4-way at g*8.
        float acc[8][8];
#pragma unroll
        for (int i = 0; i < 8; ++i)
#pragma unroll
            for (int j = 0; j < 8; ++j) acc[i][j] = 0.0f;
        float acc2[8];
#pragma unroll
        for (int j = 0; j < 8; ++j) acc2[j] = 0.0f;

        for (int kk = 0; kk < 16; ++kk) {
            // gathered tiles: scalar (random sp per position)
#pragma unroll
            for (int r = 0; r < 8; ++r) {
                int kl = r * 2 + khalf;
                int kgl = (kk * 16 + kl) * HW;
                sm.ce.As [kl][pl] = (sp1g >= 0) ? k1f[kgl + sp1g] : 0.0f;
                sm.ce.As2[kl][pl] = (sp2g >= 0) ? k2f[kgl + sp2g] : 0.0f;
            }
            // q1T tile: contiguous rows -> float4 staging (coalesced dwordx4
            // global load + ds_write_b128), 2 per thread instead of 8 scalars
#pragma unroll
            for (int it = 0; it < 2; ++it) {
                int idx = it * 256 + tid;    // 0..511 float4 slots
                int row = idx >> 5;          // 0..15
                int c4  = (idx & 31) * 4;    // 0..124
                *(float4*)&sm.ce.Bs[row][c4] =
                    *(const float4*)&q1T[(kk * 16 + row) * NC + c4];
            }
            __syncthreads();
#pragma unroll
            for (int k = 0; k < 16; ++k) {
                float a[8], bb[8];
                *(float4*)&a[0]  = *(const float4*)&sm.ce.As[k][tp * 4];
                *(float4*)&a[4]  = *(const float4*)&sm.ce.As[k][64 + tp * 4];
                *(float4*)&bb[0] = *(const float4*)&sm.ce.Bs[k][tc * 4];
                *(float4*)&bb[4] = *(const float4*)&sm.ce.Bs[k][64 + tc * 4];
#pragma unroll
                for (int i = 0; i < 8; ++i)
#pragma unroll
                    for (int j = 0; j < 8; ++j) acc[i][j] += a[i] * bb[j];
                // pseudo-label dots: k2 row for position p2, 8 of 16 anchors
                float a2 = sm.ce.As2[k][p2];
#pragma unroll
                for (int j = 0; j < 8; ++j)
                    acc2[j] += a2 * sm.ce.Bs[k][vid * 16 + half * 8 + j];
            }
            __syncthreads();
        }

        // ---- pseudo-label argmax with first-index tie-break ----
        {
            float bv = acc2[0]; int bj = 0;
#pragma unroll
            for (int j = 1; j < 8; ++j) if (acc2[j] > bv) { bv = acc2[j]; bj = j; }
            int bidx = half * 8 + bj;
            float ov = __shfl_xor(bv, 1);
            int  oi  = __shfl_xor(bidx, 1);
            if (ov > bv || (ov == bv && oi < bidx)) { bv = ov; bidx = oi; }
            if (half == 0) sm.ce.pseudoLds[p2] = vid * 16 + bidx;
        }
        __syncthreads();

        // ---- epilogue: CE per position, sum over block ----
        // row of acc[i]: p = tp*4+i (i<4) | 64+tp*4+(i-4); col of acc[][j]:
        // cj = tc*4+j (j<4) | 64+tc*4+(j-4). LSE is order-invariant; pseudo
        // match uses explicit cj.
        float cesum = 0.0f;
#pragma unroll
        for (int i = 0; i < 8; ++i) {
            int p = (i < 4) ? (tp * 4 + i) : (64 + tp * 4 + (i - 4));
            float v[8];
            float m = -INFINITY;
#pragma unroll
            for (int j = 0; j < 8; ++j) { v[j] = acc[i][j] / 25.0f; m = fmaxf(m, v[j]); }
#pragma unroll
            for (int s = 1; s < 16; s <<= 1) m = fmaxf(m, __shfl_xor(m, s));
            float sum = 0.0f;
#pragma unroll
            for (int j = 0; j < 8; ++j) sum += expf(v[j] - m);
#pragma unroll
            for (int s = 1; s < 16; s <<= 1) sum += __shfl_xor(sum, s);
            int ps = sm.ce.pseudoLds[p];
            float pv = 0.0f;
#pragma unroll
            for (int j = 0; j < 8; ++j) {
                int cj = (j < 4) ? (tc * 4 + j) : (64 + tc * 4 + (j - 4));
                pv += (cj == ps) ? v[j] : 0.0f;
            }
#pragma unroll
            for (int s = 1; s < 16; s <<= 1) pv += __shfl_xor(pv, s);
            float ce = m + logf(sum) - pv;
            if (tc == 0) cesum += ce;
        }
        for (int s = 1; s < 64; s <<= 1) cesum += __shfl_xor(cesum, s);
        if ((tid & 63) == 0) sm.ce.wpart[tid >> 6] = cesum;
        __syncthreads();
        if (tid == 0)
            atomicAdd(&wsf[0], sm.ce.wpart[0] + sm.ce.wpart[1] + sm.ce.wpart[2] + sm.ce.wpart[3]);

    } else if (blockIdx.x < CE_BLOCKS + OHEM_BLOCKS) {
        // ================= OHEM path =================
        // kg == bi%8 == XCD lane: channel slices are disjoint per XCD already.
        int bi = blockIdx.x - CE_BLOCKS;
        int n  = bi >> 3;
        int kg = bi & 7;

        const float4* g4 = (const float4*)(aff_grid + n * HW * 2);
        for (int i = 0; i < 8; ++i) {
            int pp = i * 256 + tid;          // pair index: positions 2*pp, 2*pp+1
            float4 gv = g4[pp];
            float ix0 = reflect64((gv.x + 1.0f) * 32.0f - 0.5f);
            float iy0 = reflect64((gv.y + 1.0f) * 32.0f - 0.5f);
            float ix1 = reflect64((gv.z + 1.0f) * 32.0f - 0.5f);
            float iy1 = reflect64((gv.w + 1.0f) * 32.0f - 0.5f);
            int jx0 = min(63, max(0, (int)rintf(ix0)));
            int jy0 = min(63, max(0, (int)rintf(iy0)));
            int jx1 = min(63, max(0, (int)rintf(ix1)));
            int jy1 = min(63, max(0, (int)rintf(iy1)));
            sm.oh.spos[2 * pp]     = (unsigned short)(jy0 * 64 + jx0);
            sm.oh.spos[2 * pp + 1] = (unsigned short)(jy1 * 64 + jx1);
        }
        __syncthreads();

        float sacc = 0.0f;
        for (int kk = 0; kk < 32; ++kk) {
            int k = kg * 32 + kk;
            const float* s1 = k1 + (n * KC + k) * HW;
            const float* s2 = k2 + (n * KC + k) * HW;
            for (int i = 0; i < 4; ++i) {
                int p = (i * 256 + tid) * 4;
                float4 v2 = *(const float4*)&s2[p];
                float d0 = s1[sm.oh.spos[p + 0]] - v2.x;
                float d1 = s1[sm.oh.spos[p + 1]] - v2.y;
                float d2 = s1[sm.oh.spos[p + 2]] - v2.z;
                float d3 = s1[sm.oh.spos[p + 3]] - v2.w;
                float a0 = fabsf(d0), a1 = fabsf(d1), a2 = fabsf(d2), a3 = fabsf(d3);
                sacc += (a0 < 0.5f) ? d0 * d0 : a0 - 0.25f;
                sacc += (a1 < 0.5f) ? d1 * d1 : a1 - 0.25f;
                sacc += (a2 < 0.5f) ? d2 * d2 : a2 - 0.25f;
                sacc += (a3 < 0.5f) ? d3 * d3 : a3 - 0.25f;
            }
        }
        for (int s = 1; s < 64; s <<= 1) sacc += __shfl_xor(sacc, s);
        if ((tid & 63) == 0) sm.oh.wpart[tid >> 6] = sacc;
        __syncthreads();
        if (tid == 0)
            atomicAdd(&wsf[2 + n], sm.oh.wpart[0] + sm.oh.wpart[1] + sm.oh.wpart[2] + sm.oh.wpart[3]);

    } else {
        // ================= ref-loss path =================
        int i = blockIdx.x - (CE_BLOCKS + OHEM_BLOCKS);
        bool act = tid < 128;
        int j = tid & 127;
        sm.rf.xr[tid] = x1[i * 256 + tid];   // 256 threads load the row
        __syncthreads();
        float d = 0.0f;
        if (act) {
            const float* yrow = y1 + j * 256;
#pragma unroll 8
            for (int k = 0; k < 256; ++k) d += sm.rf.xr[k] * yrow[k];
        }
        float lg = d / 25.0f;                // exact: matches reference vals/TEMP
        if (act && j == i) sm.rf.liish = lg;
        float m = act ? lg : -INFINITY;
        for (int s = 1; s < 64; s <<= 1) m = fmaxf(m, __shfl_xor(m, s));
        if (act && (tid & 63) == 0) sm.rf.wred[tid >> 6] = m;
        __syncthreads();
        m = fmaxf(sm.rf.wred[0], sm.rf.wred[1]);
        float e = act ? expf(lg - m) : 0.0f;
        for (int s = 1; s < 64; s <<= 1) e += __shfl_xor(e, s);
        if (act && (tid & 63) == 0) sm.rf.wsum[tid >> 6] = e;
        __syncthreads();
        if (tid == 0) {
            float lse = m + logf(sm.rf.wsum[0] + sm.rf.wsum[1]);
            atomicAdd(&wsf[1], lse - sm.rf.liish);
        }
    }
}

// ---------------------------------------------------------------------------
// finalize — OHEM rank-select + combine
// ---------------------------------------------------------------------------
__global__ void finalize_kernel(const float* __restrict__ wsf, float* __restrict__ out) {
    __shared__ float pf[32];
    int tid = threadIdx.x;
    if (tid < 32) pf[tid] = wsf[2 + tid] * (1.0f / 1048576.0f);  // mean over K*H*W (2^20)
    __syncthreads();
    float sel = 0.0f;
    if (tid < 32) {
        float v = pf[tid];
        int rank = 0;
        for (int j = 0; j < 32; ++j) {
            float u = pf[j];
            rank += (u < v) || (u == v && j < tid);
        }
        if (rank >= 12) sel = v;          // OHEM slice [12:32)
    }
    for (int s = 1; s < 64; s <<= 1) sel += __shfl_xor(sel, s);
    if (tid == 0) {
        float loss_ohem = sel / 20.0f;
        float loss_temp = wsf[0] / 98304.0f;   // mean over B*(T-1)*H*W
        float loss_ref  = wsf[1] / 128.0f;
        out[0] = loss_temp + loss_ohem + 0.1f * loss_ref;
    }
}

// ---------------------------------------------------------------------------
extern "C" void kernel_launch(void* const* d_in, const int* in_sizes, int n_in,
                              void* d_out, int out_size, void* d_ws, size_t ws_size,
                              hipStream_t stream) {
    const float* k1    = (const float*)d_in[0];
    const float* k2    = (const float*)d_in[1];
    const float* am1   = (const float*)d_in[2];
    const float* am2   = (const float*)d_in[3];
    const float* agrid = (const float*)d_in[4];
    const int*   hwi   = (const int*)d_in[5];
    const int*   hwir  = (const int*)d_in[6];
    float* out = (float*)d_out;
    float* wsf = (float*)d_ws;

    float* q1T = wsf + 64;               // [256][128]
    float* x1  = q1T + 256 * 128;        // [128][256]
    float* y1  = x1 + 128 * 256;         // [128][256]

    hipLaunchKernelGGL(prep_kernel, dim3(257), dim3(256), 0, stream,
                       k1, k2, am1, am2, hwi, hwir, wsf, q1T, x1, y1);
    hipLaunchKernelGGL(mega_kernel, dim3(MEGA_BLOCKS), dim3(256), 0, stream,
                       k1, k2, am1, am2, agrid, q1T, x1, y1, wsf);
    hipLaunchKernelGGL(finalize_kernel, dim3(1), dim3(64), 0, stream, wsf, out);
}